// Round 1
// baseline (651.392 us; speedup 1.0000x reference)
//
#include <hip/hip_runtime.h>
#include <hip/hip_bf16.h>

#define N_TOK 4096
#define C_DIM 1024
#define H_DIM 2048
#define V_DIM 32000
#define NE_MLP 8
#define NE_TOT 10

typedef __attribute__((ext_vector_type(8))) short bf16x8;
typedef __attribute__((ext_vector_type(4))) float f32x4;

#define BM 128
#define BN 128
#define BK 32
#define LSTR 40   // LDS row stride (bf16 elems): 80 B, 16B-aligned, breaks pow2 banking

__device__ __forceinline__ void cvt_store4(__hip_bfloat16* p, f32x4 v) {
    __hip_bfloat162 h0, h1;
    h0.x = __float2bfloat16(v.x); h0.y = __float2bfloat16(v.y);
    h1.x = __float2bfloat16(v.z); h1.y = __float2bfloat16(v.w);
    *reinterpret_cast<__hip_bfloat162*>(p)     = h0;
    *reinterpret_cast<__hip_bfloat162*>(p + 2) = h1;
}

// ---------------- router: scores, top-2, expert lists ----------------
__global__ void __launch_bounds__(256) router_kernel(
    const float* __restrict__ x, const float* __restrict__ rw,
    const float* __restrict__ rb, int* __restrict__ tok_list,
    float* __restrict__ wt_list, float* __restrict__ vw, int* __restrict__ cnt)
{
    const int lane = threadIdx.x & 63;
    const int n = blockIdx.x * 4 + (threadIdx.x >> 6);
    const float* xr = x + (size_t)n * C_DIM;

    float acc[NE_TOT];
    #pragma unroll
    for (int e = 0; e < NE_TOT; ++e) acc[e] = 0.f;

    for (int kk = 0; kk < C_DIM / 64; ++kk) {
        float xv = xr[kk * 64 + lane];
        #pragma unroll
        for (int e = 0; e < NE_TOT; ++e)
            acc[e] += xv * rw[e * C_DIM + kk * 64 + lane];
    }
    #pragma unroll
    for (int e = 0; e < NE_TOT; ++e) {
        for (int m = 32; m > 0; m >>= 1) acc[e] += __shfl_xor(acc[e], m, 64);
    }

    if (lane == 0) {
        float s[NE_TOT], sb[NE_TOT];
        #pragma unroll
        for (int e = 0; e < NE_TOT; ++e) {
            s[e]  = 1.f / (1.f + expf(-acc[e]));
            sb[e] = s[e] + rb[e];
        }
        int i0 = 0;
        #pragma unroll
        for (int e = 1; e < NE_TOT; ++e) if (sb[e] > sb[i0]) i0 = e;
        int i1 = (i0 == 0) ? 1 : 0;
        #pragma unroll
        for (int e = 0; e < NE_TOT; ++e)
            if (e != i0 && sb[e] > sb[i1]) i1 = e;

        float w0 = s[i0], w1 = s[i1];
        float inv = 1.f / (w0 + w1);
        w0 *= inv; w1 *= inv;

        float wv0 = 0.f, wv1 = 0.f;
        int   idx[2] = {i0, i1};
        float wt[2]  = {w0, w1};
        #pragma unroll
        for (int k = 0; k < 2; ++k) {
            if (idx[k] < NE_MLP) {
                int p = atomicAdd(&cnt[idx[k]], 1);
                tok_list[idx[k] * N_TOK + p] = n;
                wt_list[idx[k] * N_TOK + p] = wt[k];
            } else if (idx[k] == NE_MLP) {
                wv0 = wt[k];
            } else {
                wv1 = wt[k];
            }
        }
        vw[n * 2 + 0] = wv0;
        vw[n * 2 + 1] = wv1;
    }
}

// ---------------- tiny exclusive scan of expert counts ----------------
__global__ void scan_kernel(const int* __restrict__ cnt, int* __restrict__ offs)
{
    if (threadIdx.x == 0) {
        int o = 0;
        for (int e = 0; e < NE_MLP; ++e) { offs[e] = o; o += cnt[e]; }
    }
}

// ---------------- ve gather + output init ----------------
__global__ void __launch_bounds__(256) ve_kernel(
    const int* __restrict__ token_ids, const float* __restrict__ vt,
    const float* __restrict__ vw, float* __restrict__ out)
{
    const int n = blockIdx.x;
    const int t = token_ids[n];
    const float w0 = vw[n * 2 + 0];
    const float w1 = vw[n * 2 + 1];
    const f32x4* r0 = reinterpret_cast<const f32x4*>(vt + (size_t)t * C_DIM);
    const f32x4* r1 = reinterpret_cast<const f32x4*>(vt + ((size_t)V_DIM + t) * C_DIM);
    f32x4* o = reinterpret_cast<f32x4*>(out + (size_t)n * C_DIM);
    const int c = threadIdx.x;   // 256 threads * 4 floats = 1024 = C_DIM
    f32x4 v = {0.f, 0.f, 0.f, 0.f};
    if (w0 != 0.f) { f32x4 a = r0[c]; v += w0 * a; }
    if (w1 != 0.f) { f32x4 a = r1[c]; v += w1 * a; }
    o[c] = v;
}

// ---------------- grouped up-proj: hidden = relu(x @ w_up^T)^2 ----------------
__global__ void __launch_bounds__(256) up_kernel(
    const float* __restrict__ x, const float* __restrict__ w_up,
    const int* __restrict__ tok_list, const int* __restrict__ cnt,
    const int* __restrict__ offs, __hip_bfloat16* __restrict__ hidden)
{
    const int e = blockIdx.z;
    const int count = cnt[e];
    const int m0 = blockIdx.y * BM;
    if (m0 >= count) return;
    const int n0 = blockIdx.x * BN;
    const int base = offs[e];

    __shared__ __hip_bfloat16 lA[BM][LSTR];
    __shared__ __hip_bfloat16 lB[BN][LSTR];

    const int tid  = threadIdx.x;
    const int lane = tid & 63;
    const int wm = ((tid >> 6) >> 1) * 64;
    const int wn = ((tid >> 6) & 1) * 64;

    const int rowA = tid >> 3;        // 0..31
    const int colA = (tid & 7) * 4;   // 0..28

    const float* __restrict__ wB = w_up + (size_t)e * H_DIM * C_DIM;

    int tokr[4];
    #pragma unroll
    for (int i = 0; i < 4; ++i) {
        int r = m0 + rowA + i * 32;
        tokr[i] = tok_list[e * N_TOK + (r < count ? r : count - 1)];
    }

    f32x4 acc[4][4];
    #pragma unroll
    for (int i = 0; i < 4; ++i)
        #pragma unroll
        for (int j = 0; j < 4; ++j)
            acc[i][j] = (f32x4){0.f, 0.f, 0.f, 0.f};

    const int fm = lane & 15;
    const int fk = (lane >> 4) * 8;

    for (int k0 = 0; k0 < C_DIM; k0 += BK) {
        __syncthreads();
        #pragma unroll
        for (int i = 0; i < 4; ++i) {
            const int row = rowA + i * 32;
            f32x4 a = *reinterpret_cast<const f32x4*>(x  + (size_t)tokr[i] * C_DIM + k0 + colA);
            f32x4 b = *reinterpret_cast<const f32x4*>(wB + (size_t)(n0 + row) * C_DIM + k0 + colA);
            cvt_store4(&lA[row][colA], a);
            cvt_store4(&lB[row][colA], b);
        }
        __syncthreads();
        bf16x8 af[4], bfr[4];
        #pragma unroll
        for (int i = 0; i < 4; ++i) {
            af[i]  = *reinterpret_cast<const bf16x8*>(&lA[wm + i * 16 + fm][fk]);
            bfr[i] = *reinterpret_cast<const bf16x8*>(&lB[wn + i * 16 + fm][fk]);
        }
        #pragma unroll
        for (int i = 0; i < 4; ++i)
            #pragma unroll
            for (int j = 0; j < 4; ++j)
                acc[i][j] = __builtin_amdgcn_mfma_f32_16x16x32_bf16(af[i], bfr[j], acc[i][j], 0, 0, 0);
    }

    const int fr = (lane >> 4) * 4;
    #pragma unroll
    for (int i = 0; i < 4; ++i) {
        #pragma unroll
        for (int r = 0; r < 4; ++r) {
            const int gr = m0 + wm + i * 16 + fr + r;
            if (gr < count) {
                __hip_bfloat16* hrow = hidden + (size_t)(base + gr) * H_DIM + n0 + wn + fm;
                #pragma unroll
                for (int j = 0; j < 4; ++j) {
                    float v = acc[i][j][r];
                    v = v > 0.f ? v * v : 0.f;
                    hrow[j * 16] = __float2bfloat16(v);
                }
            }
        }
    }
}

// ---------------- grouped down-proj: out += w * (hidden @ w_down^T) ----------------
__global__ void __launch_bounds__(256) down_kernel(
    const __hip_bfloat16* __restrict__ hidden, const float* __restrict__ w_down,
    const int* __restrict__ tok_list, const float* __restrict__ wt_list,
    const int* __restrict__ cnt, const int* __restrict__ offs,
    float* __restrict__ out)
{
    const int e = blockIdx.z;
    const int count = cnt[e];
    const int m0 = blockIdx.y * BM;
    if (m0 >= count) return;
    const int n0 = blockIdx.x * BN;
    const int base = offs[e];

    __shared__ __hip_bfloat16 lA[BM][LSTR];
    __shared__ __hip_bfloat16 lB[BN][LSTR];

    const int tid  = threadIdx.x;
    const int lane = tid & 63;
    const int wm = ((tid >> 6) >> 1) * 64;
    const int wn = ((tid >> 6) & 1) * 64;

    // A staging (bf16 direct): 128 rows x 32 cols, 16B per thread x 2 passes
    const int rowA = tid >> 2;        // 0..63
    const int colA = (tid & 3) * 8;   // 0,8,16,24
    int arow[2];
    #pragma unroll
    for (int i = 0; i < 2; ++i) {
        int r = m0 + rowA + i * 64;
        arow[i] = base + (r < count ? r : count - 1);
    }
    // B staging (fp32 -> bf16)
    const int rowB = tid >> 3;        // 0..31
    const int colB = (tid & 7) * 4;
    const float* __restrict__ wB = w_down + (size_t)e * C_DIM * H_DIM;

    f32x4 acc[4][4];
    #pragma unroll
    for (int i = 0; i < 4; ++i)
        #pragma unroll
        for (int j = 0; j < 4; ++j)
            acc[i][j] = (f32x4){0.f, 0.f, 0.f, 0.f};

    const int fm = lane & 15;
    const int fk = (lane >> 4) * 8;

    for (int k0 = 0; k0 < H_DIM; k0 += BK) {
        __syncthreads();
        #pragma unroll
        for (int i = 0; i < 2; ++i) {
            bf16x8 a = *reinterpret_cast<const bf16x8*>(
                hidden + (size_t)arow[i] * H_DIM + k0 + colA);
            *reinterpret_cast<bf16x8*>(&lA[rowA + i * 64][colA]) = a;
        }
        #pragma unroll
        for (int i = 0; i < 4; ++i) {
            f32x4 b = *reinterpret_cast<const f32x4*>(
                wB + (size_t)(n0 + rowB + i * 32) * H_DIM + k0 + colB);
            cvt_store4(&lB[rowB + i * 32][colB], b);
        }
        __syncthreads();
        bf16x8 af[4], bfr[4];
        #pragma unroll
        for (int i = 0; i < 4; ++i) {
            af[i]  = *reinterpret_cast<const bf16x8*>(&lA[wm + i * 16 + fm][fk]);
            bfr[i] = *reinterpret_cast<const bf16x8*>(&lB[wn + i * 16 + fm][fk]);
        }
        #pragma unroll
        for (int i = 0; i < 4; ++i)
            #pragma unroll
            for (int j = 0; j < 4; ++j)
                acc[i][j] = __builtin_amdgcn_mfma_f32_16x16x32_bf16(af[i], bfr[j], acc[i][j], 0, 0, 0);
    }

    const int fr = (lane >> 4) * 4;
    #pragma unroll
    for (int i = 0; i < 4; ++i) {
        #pragma unroll
        for (int r = 0; r < 4; ++r) {
            const int gr = m0 + wm + i * 16 + fr + r;
            if (gr < count) {
                const int   t = tok_list[e * N_TOK + gr];
                const float w = wt_list[e * N_TOK + gr];
                float* orow = out + (size_t)t * C_DIM + n0 + wn + fm;
                #pragma unroll
                for (int j = 0; j < 4; ++j)
                    atomicAdd(&orow[j * 16], w * acc[i][j][r]);
            }
        }
    }
}

extern "C" void kernel_launch(void* const* d_in, const int* in_sizes, int n_in,
                              void* d_out, int out_size, void* d_ws, size_t ws_size,
                              hipStream_t stream)
{
    const float* x         = (const float*)d_in[0];
    const int*   token_ids = (const int*)  d_in[1];
    const float* w_up      = (const float*)d_in[2];
    const float* w_down    = (const float*)d_in[3];
    const float* router_w  = (const float*)d_in[4];
    const float* router_b  = (const float*)d_in[5];
    const float* ve_tables = (const float*)d_in[6];
    float* out = (float*)d_out;

    char* ws = (char*)d_ws;
    __hip_bfloat16* hidden = (__hip_bfloat16*)ws;          // 8192 * 2048 * 2 B = 32 MiB
    size_t off = (size_t)8192 * H_DIM * 2;
    int*   tok_list = (int*)  (ws + off); off += (size_t)NE_MLP * N_TOK * 4;
    float* wt_list  = (float*)(ws + off); off += (size_t)NE_MLP * N_TOK * 4;
    float* vw       = (float*)(ws + off); off += (size_t)N_TOK * 2 * 4;
    int*   cnt      = (int*)  (ws + off); off += 32;
    int*   offs     = (int*)  (ws + off);

    hipMemsetAsync(cnt, 0, NE_MLP * sizeof(int), stream);
    router_kernel<<<N_TOK / 4, 256, 0, stream>>>(x, router_w, router_b,
                                                 tok_list, wt_list, vw, cnt);
    scan_kernel<<<1, 64, 0, stream>>>(cnt, offs);
    ve_kernel<<<N_TOK, 256, 0, stream>>>(token_ids, ve_tables, vw, out);
    up_kernel<<<dim3(H_DIM / BN, N_TOK / BM, NE_MLP), 256, 0, stream>>>(
        x, w_up, tok_list, cnt, offs, hidden);
    down_kernel<<<dim3(C_DIM / BN, N_TOK / BM, NE_MLP), 256, 0, stream>>>(
        hidden, w_down, tok_list, wt_list, cnt, offs, out);
}

// Round 2
// 595.423 us; speedup vs baseline: 1.0940x; 1.0940x over previous
//
#include <hip/hip_runtime.h>
#include <hip/hip_bf16.h>
#include <stdint.h>

#define N_TOK 4096
#define C_DIM 1024
#define H_DIM 2048
#define V_DIM 32000
#define NE_MLP 8
#define NE_TOT 10

typedef __attribute__((ext_vector_type(8))) short bf16x8;
typedef __attribute__((ext_vector_type(4))) short bf16x4;
typedef __attribute__((ext_vector_type(4))) float f32x4;

#define BM 128
#define BN 128
#define BK 32

__device__ __forceinline__ void gload16(const void* g, void* l) {
    __builtin_amdgcn_global_load_lds(
        (const __attribute__((address_space(1))) void*)g,
        (__attribute__((address_space(3))) void*)l,
        16, 0, 0);
}

__device__ __forceinline__ unsigned short bf16bits(float v) {
    __hip_bfloat16 h = __float2bfloat16(v);
    return *reinterpret_cast<unsigned short*>(&h);
}

// ---------------- fp32 -> bf16 convert (memory-bound) ----------------
__global__ void __launch_bounds__(256) cvt_kernel(
    const float* __restrict__ src, __hip_bfloat16* __restrict__ dst)
{
    const int i = blockIdx.x * 256 + threadIdx.x;
    f32x4 v = reinterpret_cast<const f32x4*>(src)[i];
    bf16x4 b;
    b.x = (short)bf16bits(v.x); b.y = (short)bf16bits(v.y);
    b.z = (short)bf16bits(v.z); b.w = (short)bf16bits(v.w);
    reinterpret_cast<bf16x4*>(dst)[i] = b;
}

// ---------------- router: scores, top-2, expert lists ----------------
__global__ void __launch_bounds__(256) router_kernel(
    const float* __restrict__ x, const float* __restrict__ rw,
    const float* __restrict__ rb, int* __restrict__ tok_list,
    int* __restrict__ te, int* __restrict__ tp, float* __restrict__ tw,
    float* __restrict__ vw, int* __restrict__ cnt)
{
    const int lane = threadIdx.x & 63;
    const int n = blockIdx.x * 4 + (threadIdx.x >> 6);
    const f32x4* xr  = reinterpret_cast<const f32x4*>(x + (size_t)n * C_DIM);
    const f32x4* rw4 = reinterpret_cast<const f32x4*>(rw);

    float acc[NE_TOT];
    #pragma unroll
    for (int e = 0; e < NE_TOT; ++e) acc[e] = 0.f;

    #pragma unroll
    for (int kk = 0; kk < C_DIM / 256; ++kk) {
        f32x4 xv = xr[kk * 64 + lane];
        #pragma unroll
        for (int e = 0; e < NE_TOT; ++e) {
            f32x4 wv = rw4[e * (C_DIM / 4) + kk * 64 + lane];
            acc[e] += xv.x * wv.x + xv.y * wv.y + xv.z * wv.z + xv.w * wv.w;
        }
    }
    #pragma unroll
    for (int e = 0; e < NE_TOT; ++e) {
        for (int m = 32; m > 0; m >>= 1) acc[e] += __shfl_xor(acc[e], m, 64);
    }

    if (lane == 0) {
        float s[NE_TOT], sb[NE_TOT];
        #pragma unroll
        for (int e = 0; e < NE_TOT; ++e) {
            s[e]  = 1.f / (1.f + expf(-acc[e]));
            sb[e] = s[e] + rb[e];
        }
        int i0 = 0;
        #pragma unroll
        for (int e = 1; e < NE_TOT; ++e) if (sb[e] > sb[i0]) i0 = e;
        int i1 = (i0 == 0) ? 1 : 0;
        #pragma unroll
        for (int e = 0; e < NE_TOT; ++e)
            if (e != i0 && sb[e] > sb[i1]) i1 = e;

        float w0 = s[i0], w1 = s[i1];
        float inv = 1.f / (w0 + w1);
        w0 *= inv; w1 *= inv;

        float wv0 = 0.f, wv1 = 0.f;
        int   idx[2] = {i0, i1};
        float wt[2]  = {w0, w1};
        #pragma unroll
        for (int k = 0; k < 2; ++k) {
            if (idx[k] < NE_MLP) {
                int p = atomicAdd(&cnt[idx[k]], 1);
                tok_list[idx[k] * N_TOK + p] = n;
                te[n * 2 + k] = idx[k];
                tp[n * 2 + k] = p;
                tw[n * 2 + k] = wt[k];
            } else {
                te[n * 2 + k] = -1;
                tp[n * 2 + k] = 0;
                tw[n * 2 + k] = 0.f;
                if (idx[k] == NE_MLP) wv0 = wt[k]; else wv1 = wt[k];
            }
        }
        vw[n * 2 + 0] = wv0;
        vw[n * 2 + 1] = wv1;
    }
}

// ---------------- tiny exclusive scan of expert counts ----------------
__global__ void scan_kernel(const int* __restrict__ cnt, int* __restrict__ offs)
{
    if (threadIdx.x == 0) {
        int o = 0;
        for (int e = 0; e < NE_MLP; ++e) { offs[e] = o; o += cnt[e]; }
    }
}

// ---------------- grouped up-proj: hidden = relu(x @ w_up^T)^2 (bf16 out) ----
__global__ void __launch_bounds__(256) up_kernel(
    const __hip_bfloat16* __restrict__ xb, const __hip_bfloat16* __restrict__ wub,
    const int* __restrict__ tok_list, const int* __restrict__ cnt,
    const int* __restrict__ offs, __hip_bfloat16* __restrict__ hidden)
{
    const int e = blockIdx.z;
    const int count = cnt[e];
    const int m0 = blockIdx.y * BM;
    if (m0 >= count) return;
    const int n0 = blockIdx.x * BN;
    const int base = offs[e];

    __shared__ __hip_bfloat16 lA[BM * BK];
    __shared__ __hip_bfloat16 lB[BN * BK];

    const int tid  = threadIdx.x;
    const int lane = tid & 63;
    const int wv   = tid >> 6;
    const int wm = (wv >> 1) * 64;
    const int wn = (wv & 1) * 64;

    // staging: segment seg = wv + 4t covers rows seg*16..+15 (64B/row)
    const __hip_bfloat16* ga[2];
    const __hip_bfloat16* gb[2];
    __hip_bfloat16* la[2];
    __hip_bfloat16* lb[2];
    const __hip_bfloat16* wB = wub + (size_t)e * H_DIM * C_DIM;
    #pragma unroll
    for (int t = 0; t < 2; ++t) {
        const int srow = (wv + 4 * t) * 16 + (lane >> 2);
        int r = m0 + srow;
        const int tok = tok_list[e * N_TOK + (r < count ? r : count - 1)];
        ga[t] = xb + (size_t)tok * C_DIM + (lane & 3) * 8;
        gb[t] = wB + (size_t)(n0 + srow) * C_DIM + (lane & 3) * 8;
        la[t] = lA + (wv + 4 * t) * 512;
        lb[t] = lB + (wv + 4 * t) * 512;
    }

    f32x4 acc[4][4];
    #pragma unroll
    for (int i = 0; i < 4; ++i)
        #pragma unroll
        for (int j = 0; j < 4; ++j)
            acc[i][j] = (f32x4){0.f, 0.f, 0.f, 0.f};

    const int fm  = lane & 15;
    const int fkb = (lane >> 4) * 8;

    for (int k0 = 0; k0 < C_DIM; k0 += BK) {
        __syncthreads();
        #pragma unroll
        for (int t = 0; t < 2; ++t) {
            gload16(ga[t], la[t]);
            gload16(gb[t], lb[t]);
            ga[t] += BK; gb[t] += BK;
        }
        __syncthreads();
        bf16x8 af[4], bfr[4];
        #pragma unroll
        for (int i = 0; i < 4; ++i) {
            af[i]  = *reinterpret_cast<const bf16x8*>(lA + (wm + i * 16 + fm) * BK + fkb);
            bfr[i] = *reinterpret_cast<const bf16x8*>(lB + (wn + i * 16 + fm) * BK + fkb);
        }
        #pragma unroll
        for (int i = 0; i < 4; ++i)
            #pragma unroll
            for (int j = 0; j < 4; ++j)
                acc[i][j] = __builtin_amdgcn_mfma_f32_16x16x32_bf16(af[i], bfr[j], acc[i][j], 0, 0, 0);
    }

    const int fr = (lane >> 4) * 4;
    #pragma unroll
    for (int i = 0; i < 4; ++i) {
        #pragma unroll
        for (int r = 0; r < 4; ++r) {
            const int gr = m0 + wm + i * 16 + fr + r;
            const bool ok = gr < count;
            unsigned int pk[4];
            #pragma unroll
            for (int j = 0; j < 4; ++j) {
                float v = acc[i][j][r];
                v = v > 0.f ? v * v : 0.f;
                unsigned short b = bf16bits(v);
                int other = __shfl_xor((int)b, 1, 64);
                pk[j] = (unsigned)b | ((unsigned)other << 16);
            }
            if (ok && !(lane & 1)) {
                __hip_bfloat16* hrow = hidden + (size_t)(base + gr) * H_DIM + n0 + wn + fm;
                #pragma unroll
                for (int j = 0; j < 4; ++j)
                    *reinterpret_cast<unsigned int*>(hrow + j * 16) = pk[j];
            }
        }
    }
}

// ---------------- grouped down-proj: mlp_buf = hidden @ w_down^T (fp32) -----
__global__ void __launch_bounds__(256) down_kernel(
    const __hip_bfloat16* __restrict__ hidden, const __hip_bfloat16* __restrict__ wdb,
    const int* __restrict__ cnt, const int* __restrict__ offs,
    float* __restrict__ mlp_buf)
{
    const int e = blockIdx.z;
    const int count = cnt[e];
    const int m0 = blockIdx.y * BM;
    if (m0 >= count) return;
    const int n0 = blockIdx.x * BN;
    const int base = offs[e];

    __shared__ __hip_bfloat16 lA[BM * BK];
    __shared__ __hip_bfloat16 lB[BN * BK];

    const int tid  = threadIdx.x;
    const int lane = tid & 63;
    const int wv   = tid >> 6;
    const int wm = (wv >> 1) * 64;
    const int wn = (wv & 1) * 64;

    const __hip_bfloat16* ga[2];
    const __hip_bfloat16* gb[2];
    __hip_bfloat16* la[2];
    __hip_bfloat16* lb[2];
    const __hip_bfloat16* wB = wdb + (size_t)e * C_DIM * H_DIM;
    #pragma unroll
    for (int t = 0; t < 2; ++t) {
        const int srow = (wv + 4 * t) * 16 + (lane >> 2);
        int r = m0 + srow;
        const int arow = base + (r < count ? r : count - 1);
        ga[t] = hidden + (size_t)arow * H_DIM + (lane & 3) * 8;
        gb[t] = wB + (size_t)(n0 + srow) * H_DIM + (lane & 3) * 8;
        la[t] = lA + (wv + 4 * t) * 512;
        lb[t] = lB + (wv + 4 * t) * 512;
    }

    f32x4 acc[4][4];
    #pragma unroll
    for (int i = 0; i < 4; ++i)
        #pragma unroll
        for (int j = 0; j < 4; ++j)
            acc[i][j] = (f32x4){0.f, 0.f, 0.f, 0.f};

    const int fm  = lane & 15;
    const int fkb = (lane >> 4) * 8;

    for (int k0 = 0; k0 < H_DIM; k0 += BK) {
        __syncthreads();
        #pragma unroll
        for (int t = 0; t < 2; ++t) {
            gload16(ga[t], la[t]);
            gload16(gb[t], lb[t]);
            ga[t] += BK; gb[t] += BK;
        }
        __syncthreads();
        bf16x8 af[4], bfr[4];
        #pragma unroll
        for (int i = 0; i < 4; ++i) {
            af[i]  = *reinterpret_cast<const bf16x8*>(lA + (wm + i * 16 + fm) * BK + fkb);
            bfr[i] = *reinterpret_cast<const bf16x8*>(lB + (wn + i * 16 + fm) * BK + fkb);
        }
        #pragma unroll
        for (int i = 0; i < 4; ++i)
            #pragma unroll
            for (int j = 0; j < 4; ++j)
                acc[i][j] = __builtin_amdgcn_mfma_f32_16x16x32_bf16(af[i], bfr[j], acc[i][j], 0, 0, 0);
    }

    const int fr = (lane >> 4) * 4;
    #pragma unroll
    for (int i = 0; i < 4; ++i) {
        #pragma unroll
        for (int r = 0; r < 4; ++r) {
            const int gr = m0 + wm + i * 16 + fr + r;
            if (gr < count) {
                float* orow = mlp_buf + (size_t)(base + gr) * C_DIM + n0 + wn + fm;
                #pragma unroll
                for (int j = 0; j < 4; ++j)
                    orow[j * 16] = acc[i][j][r];
            }
        }
    }
}

// ---------------- combine: out = ve contribs + weighted mlp contribs --------
__global__ void __launch_bounds__(256) combine_kernel(
    const int* __restrict__ token_ids, const float* __restrict__ vt,
    const float* __restrict__ vw, const int* __restrict__ te,
    const int* __restrict__ tp, const float* __restrict__ tw,
    const int* __restrict__ offs, const float* __restrict__ mlp_buf,
    float* __restrict__ out)
{
    const int n = blockIdx.x;
    const int c = threadIdx.x;
    const int t = token_ids[n];
    const float w0 = vw[n * 2 + 0];
    const float w1 = vw[n * 2 + 1];
    f32x4 v = {0.f, 0.f, 0.f, 0.f};
    if (w0 != 0.f)
        v += w0 * reinterpret_cast<const f32x4*>(vt + (size_t)t * C_DIM)[c];
    if (w1 != 0.f)
        v += w1 * reinterpret_cast<const f32x4*>(vt + ((size_t)V_DIM + t) * C_DIM)[c];
    #pragma unroll
    for (int k = 0; k < 2; ++k) {
        const int e = te[n * 2 + k];
        if (e >= 0) {
            const int slot = offs[e] + tp[n * 2 + k];
            v += tw[n * 2 + k] *
                 reinterpret_cast<const f32x4*>(mlp_buf + (size_t)slot * C_DIM)[c];
        }
    }
    reinterpret_cast<f32x4*>(out + (size_t)n * C_DIM)[c] = v;
}

extern "C" void kernel_launch(void* const* d_in, const int* in_sizes, int n_in,
                              void* d_out, int out_size, void* d_ws, size_t ws_size,
                              hipStream_t stream)
{
    const float* x         = (const float*)d_in[0];
    const int*   token_ids = (const int*)  d_in[1];
    const float* w_up      = (const float*)d_in[2];
    const float* w_down    = (const float*)d_in[3];
    const float* router_w  = (const float*)d_in[4];
    const float* router_b  = (const float*)d_in[5];
    const float* ve_tables = (const float*)d_in[6];
    float* out = (float*)d_out;

    char* ws = (char*)d_ws;
    size_t off = 0;
    __hip_bfloat16* hidden  = (__hip_bfloat16*)(ws + off); off += (size_t)8192 * H_DIM * 2;
    float*          mlp_buf = (float*)         (ws + off); off += (size_t)8192 * C_DIM * 4;
    __hip_bfloat16* xb      = (__hip_bfloat16*)(ws + off); off += (size_t)N_TOK * C_DIM * 2;
    __hip_bfloat16* wub     = (__hip_bfloat16*)(ws + off); off += (size_t)NE_MLP * H_DIM * C_DIM * 2;
    __hip_bfloat16* wdb     = (__hip_bfloat16*)(ws + off); off += (size_t)NE_MLP * C_DIM * H_DIM * 2;
    int*   tok_list = (int*)  (ws + off); off += (size_t)NE_MLP * N_TOK * 4;
    int*   te       = (int*)  (ws + off); off += (size_t)N_TOK * 2 * 4;
    int*   tp       = (int*)  (ws + off); off += (size_t)N_TOK * 2 * 4;
    float* tw       = (float*)(ws + off); off += (size_t)N_TOK * 2 * 4;
    float* vw       = (float*)(ws + off); off += (size_t)N_TOK * 2 * 4;
    int*   cnt      = (int*)  (ws + off); off += 64;
    int*   offs     = (int*)  (ws + off);

    hipMemsetAsync(cnt, 0, NE_MLP * sizeof(int), stream);

    cvt_kernel<<<(N_TOK * C_DIM) / 1024, 256, 0, stream>>>(x, xb);
    cvt_kernel<<<(NE_MLP * H_DIM * C_DIM) / 1024, 256, 0, stream>>>(w_up, wub);
    cvt_kernel<<<(NE_MLP * C_DIM * H_DIM) / 1024, 256, 0, stream>>>(w_down, wdb);

    router_kernel<<<N_TOK / 4, 256, 0, stream>>>(x, router_w, router_b,
                                                 tok_list, te, tp, tw, vw, cnt);
    scan_kernel<<<1, 64, 0, stream>>>(cnt, offs);

    up_kernel<<<dim3(H_DIM / BN, N_TOK / BM, NE_MLP), 256, 0, stream>>>(
        xb, wub, tok_list, cnt, offs, hidden);
    down_kernel<<<dim3(C_DIM / BN, N_TOK / BM, NE_MLP), 256, 0, stream>>>(
        hidden, wdb, cnt, offs, mlp_buf);
    combine_kernel<<<N_TOK, 256, 0, stream>>>(token_ids, ve_tables, vw,
                                              te, tp, tw, offs, mlp_buf, out);
}

// Round 3
// 589.023 us; speedup vs baseline: 1.1059x; 1.0109x over previous
//
#include <hip/hip_runtime.h>
#include <hip/hip_bf16.h>
#include <stdint.h>

#define N_TOK 4096
#define C_DIM 1024
#define H_DIM 2048
#define V_DIM 32000
#define NE_MLP 8
#define NE_TOT 10

typedef __attribute__((ext_vector_type(8))) short bf16x8;
typedef __attribute__((ext_vector_type(4))) short bf16x4;
typedef __attribute__((ext_vector_type(4))) float f32x4;

#define BM 128
#define BN 128
// K-step per barrier pair = 64, staged as two BK=32 LDS images (64B rows)
#define HKE 32            // elems per half-K
#define HALF_ELEMS (128 * 32)   // one 128-row x 32-col bf16 image

__device__ __forceinline__ void gload16(const void* g, void* l) {
    __builtin_amdgcn_global_load_lds(
        (const __attribute__((address_space(1))) void*)g,
        (__attribute__((address_space(3))) void*)l,
        16, 0, 0);
}

__device__ __forceinline__ unsigned short bf16bits(float v) {
    __hip_bfloat16 h = __float2bfloat16(v);
    return *reinterpret_cast<unsigned short*>(&h);
}

// ---------------- fused fp32 -> bf16 convert (x, w_up, w_down) --------------
#define CVT_N0 (N_TOK * C_DIM / 4)
#define CVT_N1 (NE_MLP * H_DIM * C_DIM / 4)
__global__ void __launch_bounds__(256) cvt_kernel(
    const float* __restrict__ x, const float* __restrict__ wu,
    const float* __restrict__ wd, __hip_bfloat16* __restrict__ xb,
    __hip_bfloat16* __restrict__ wub, __hip_bfloat16* __restrict__ wdb)
{
    const int i = blockIdx.x * 256 + threadIdx.x;
    const float* src;
    __hip_bfloat16* dst;
    int j;
    if (i < CVT_N0)            { src = x;  dst = xb;  j = i; }
    else if (i < CVT_N0 + CVT_N1) { src = wu; dst = wub; j = i - CVT_N0; }
    else                       { src = wd; dst = wdb; j = i - CVT_N0 - CVT_N1; }
    f32x4 v = reinterpret_cast<const f32x4*>(src)[j];
    bf16x4 b;
    b.x = (short)bf16bits(v.x); b.y = (short)bf16bits(v.y);
    b.z = (short)bf16bits(v.z); b.w = (short)bf16bits(v.w);
    reinterpret_cast<bf16x4*>(dst)[j] = b;
}

// ---------------- router: scores, top-2, expert lists ----------------
__global__ void __launch_bounds__(256) router_kernel(
    const float* __restrict__ x, const float* __restrict__ rw,
    const float* __restrict__ rb, int* __restrict__ tok_list,
    int* __restrict__ te, int* __restrict__ tp, float* __restrict__ tw,
    float* __restrict__ vw, int* __restrict__ cnt)
{
    const int lane = threadIdx.x & 63;
    const int n = blockIdx.x * 4 + (threadIdx.x >> 6);
    const f32x4* xr  = reinterpret_cast<const f32x4*>(x + (size_t)n * C_DIM);
    const f32x4* rw4 = reinterpret_cast<const f32x4*>(rw);

    float acc[NE_TOT];
    #pragma unroll
    for (int e = 0; e < NE_TOT; ++e) acc[e] = 0.f;

    #pragma unroll
    for (int kk = 0; kk < C_DIM / 256; ++kk) {
        f32x4 xv = xr[kk * 64 + lane];
        #pragma unroll
        for (int e = 0; e < NE_TOT; ++e) {
            f32x4 wv = rw4[e * (C_DIM / 4) + kk * 64 + lane];
            acc[e] += xv.x * wv.x + xv.y * wv.y + xv.z * wv.z + xv.w * wv.w;
        }
    }
    #pragma unroll
    for (int e = 0; e < NE_TOT; ++e) {
        for (int m = 32; m > 0; m >>= 1) acc[e] += __shfl_xor(acc[e], m, 64);
    }

    if (lane == 0) {
        float s[NE_TOT], sb[NE_TOT];
        #pragma unroll
        for (int e = 0; e < NE_TOT; ++e) {
            s[e]  = 1.f / (1.f + expf(-acc[e]));
            sb[e] = s[e] + rb[e];
        }
        int i0 = 0;
        #pragma unroll
        for (int e = 1; e < NE_TOT; ++e) if (sb[e] > sb[i0]) i0 = e;
        int i1 = (i0 == 0) ? 1 : 0;
        #pragma unroll
        for (int e = 0; e < NE_TOT; ++e)
            if (e != i0 && sb[e] > sb[i1]) i1 = e;

        float w0 = s[i0], w1 = s[i1];
        float inv = 1.f / (w0 + w1);
        w0 *= inv; w1 *= inv;

        float wv0 = 0.f, wv1 = 0.f;
        int   idx[2] = {i0, i1};
        float wt[2]  = {w0, w1};
        #pragma unroll
        for (int k = 0; k < 2; ++k) {
            if (idx[k] < NE_MLP) {
                int p = atomicAdd(&cnt[idx[k]], 1);
                tok_list[idx[k] * N_TOK + p] = n;
                te[n * 2 + k] = idx[k];
                tp[n * 2 + k] = p;
                tw[n * 2 + k] = wt[k];
            } else {
                te[n * 2 + k] = -1;
                tp[n * 2 + k] = 0;
                tw[n * 2 + k] = 0.f;
                if (idx[k] == NE_MLP) wv0 = wt[k]; else wv1 = wt[k];
            }
        }
        vw[n * 2 + 0] = wv0;
        vw[n * 2 + 1] = wv1;
    }
}

// ---------------- grouped up-proj: hidden = relu(x @ w_up^T)^2 (bf16 out) ----
__global__ void __launch_bounds__(256) up_kernel(
    const __hip_bfloat16* __restrict__ xb, const __hip_bfloat16* __restrict__ wub,
    const int* __restrict__ tok_list, const int* __restrict__ cnt,
    __hip_bfloat16* __restrict__ hidden)
{
    const int e = blockIdx.z;
    const int count = cnt[e];
    const int m0 = blockIdx.y * BM;
    if (m0 >= count) return;
    const int n0 = blockIdx.x * BN;

    __shared__ __hip_bfloat16 lA[2 * HALF_ELEMS];
    __shared__ __hip_bfloat16 lB[2 * HALF_ELEMS];

    const int tid  = threadIdx.x;
    const int lane = tid & 63;
    const int wv   = tid >> 6;
    const int wm = (wv >> 1) * 64;
    const int wn = (wv & 1) * 64;

    // staging: seg = wv+4t covers rows seg*16..+15 of a 32-col half (64B rows)
    const __hip_bfloat16* ga[2];
    const __hip_bfloat16* gb[2];
    __hip_bfloat16* la[2];
    __hip_bfloat16* lb[2];
    const __hip_bfloat16* wB = wub + (size_t)e * H_DIM * C_DIM;
    #pragma unroll
    for (int t = 0; t < 2; ++t) {
        const int srow = (wv + 4 * t) * 16 + (lane >> 2);
        int r = m0 + srow;
        const int tok = tok_list[e * N_TOK + (r < count ? r : count - 1)];
        ga[t] = xb + (size_t)tok * C_DIM + (lane & 3) * 8;
        gb[t] = wB + (size_t)(n0 + srow) * C_DIM + (lane & 3) * 8;
        la[t] = lA + (wv + 4 * t) * 512;
        lb[t] = lB + (wv + 4 * t) * 512;
    }

    f32x4 acc[4][4];
    #pragma unroll
    for (int i = 0; i < 4; ++i)
        #pragma unroll
        for (int j = 0; j < 4; ++j)
            acc[i][j] = (f32x4){0.f, 0.f, 0.f, 0.f};

    const int fm  = lane & 15;
    const int fkb = (lane >> 4) * 8;

    for (int k0 = 0; k0 < C_DIM; k0 += 2 * HKE) {
        __syncthreads();
        #pragma unroll
        for (int h = 0; h < 2; ++h) {
            #pragma unroll
            for (int t = 0; t < 2; ++t) {
                gload16(ga[t] + h * HKE, la[t] + h * HALF_ELEMS);
                gload16(gb[t] + h * HKE, lb[t] + h * HALF_ELEMS);
            }
        }
        #pragma unroll
        for (int t = 0; t < 2; ++t) { ga[t] += 2 * HKE; gb[t] += 2 * HKE; }
        __syncthreads();
        #pragma unroll
        for (int h = 0; h < 2; ++h) {
            bf16x8 af[4], bfr[4];
            #pragma unroll
            for (int i = 0; i < 4; ++i) {
                af[i]  = *reinterpret_cast<const bf16x8*>(lA + h * HALF_ELEMS + (wm + i * 16 + fm) * HKE + fkb);
                bfr[i] = *reinterpret_cast<const bf16x8*>(lB + h * HALF_ELEMS + (wn + i * 16 + fm) * HKE + fkb);
            }
            #pragma unroll
            for (int i = 0; i < 4; ++i)
                #pragma unroll
                for (int j = 0; j < 4; ++j)
                    acc[i][j] = __builtin_amdgcn_mfma_f32_16x16x32_bf16(af[i], bfr[j], acc[i][j], 0, 0, 0);
        }
    }

    const int fr = (lane >> 4) * 4;
    #pragma unroll
    for (int i = 0; i < 4; ++i) {
        #pragma unroll
        for (int r = 0; r < 4; ++r) {
            const int gr = m0 + wm + i * 16 + fr + r;
            const bool ok = gr < count;
            unsigned int pk[4];
            #pragma unroll
            for (int j = 0; j < 4; ++j) {
                float v = acc[i][j][r];
                v = v > 0.f ? v * v : 0.f;
                unsigned short b = bf16bits(v);
                int other = __shfl_xor((int)b, 1, 64);
                pk[j] = (unsigned)b | ((unsigned)other << 16);
            }
            if (ok && !(lane & 1)) {
                __hip_bfloat16* hrow = hidden + (size_t)(e * N_TOK + gr) * H_DIM + n0 + wn + fm;
                #pragma unroll
                for (int j = 0; j < 4; ++j)
                    *reinterpret_cast<unsigned int*>(hrow + j * 16) = pk[j];
            }
        }
    }
}

// ------- grouped down-proj (split-K=2): mlp_buf[kh] = hidden @ w_down^T -----
#define MLP_SLAB ((size_t)NE_MLP * N_TOK * C_DIM)
__global__ void __launch_bounds__(256) down_kernel(
    const __hip_bfloat16* __restrict__ hidden, const __hip_bfloat16* __restrict__ wdb,
    const int* __restrict__ cnt, float* __restrict__ mlp_buf)
{
    const int e  = blockIdx.z >> 1;
    const int kh = blockIdx.z & 1;
    const int count = cnt[e];
    const int m0 = blockIdx.y * BM;
    if (m0 >= count) return;
    const int n0 = blockIdx.x * BN;
    const int kbase = kh * (H_DIM / 2);

    __shared__ __hip_bfloat16 lA[2 * HALF_ELEMS];
    __shared__ __hip_bfloat16 lB[2 * HALF_ELEMS];

    const int tid  = threadIdx.x;
    const int lane = tid & 63;
    const int wv   = tid >> 6;
    const int wm = (wv >> 1) * 64;
    const int wn = (wv & 1) * 64;

    const __hip_bfloat16* ga[2];
    const __hip_bfloat16* gb[2];
    __hip_bfloat16* la[2];
    __hip_bfloat16* lb[2];
    const __hip_bfloat16* wB = wdb + (size_t)e * C_DIM * H_DIM;
    #pragma unroll
    for (int t = 0; t < 2; ++t) {
        const int srow = (wv + 4 * t) * 16 + (lane >> 2);
        int r = m0 + srow;
        const int arow = e * N_TOK + (r < count ? r : count - 1);
        ga[t] = hidden + (size_t)arow * H_DIM + kbase + (lane & 3) * 8;
        gb[t] = wB + (size_t)(n0 + srow) * H_DIM + kbase + (lane & 3) * 8;
        la[t] = lA + (wv + 4 * t) * 512;
        lb[t] = lB + (wv + 4 * t) * 512;
    }

    f32x4 acc[4][4];
    #pragma unroll
    for (int i = 0; i < 4; ++i)
        #pragma unroll
        for (int j = 0; j < 4; ++j)
            acc[i][j] = (f32x4){0.f, 0.f, 0.f, 0.f};

    const int fm  = lane & 15;
    const int fkb = (lane >> 4) * 8;

    for (int k0 = 0; k0 < H_DIM / 2; k0 += 2 * HKE) {
        __syncthreads();
        #pragma unroll
        for (int h = 0; h < 2; ++h) {
            #pragma unroll
            for (int t = 0; t < 2; ++t) {
                gload16(ga[t] + h * HKE, la[t] + h * HALF_ELEMS);
                gload16(gb[t] + h * HKE, lb[t] + h * HALF_ELEMS);
            }
        }
        #pragma unroll
        for (int t = 0; t < 2; ++t) { ga[t] += 2 * HKE; gb[t] += 2 * HKE; }
        __syncthreads();
        #pragma unroll
        for (int h = 0; h < 2; ++h) {
            bf16x8 af[4], bfr[4];
            #pragma unroll
            for (int i = 0; i < 4; ++i) {
                af[i]  = *reinterpret_cast<const bf16x8*>(lA + h * HALF_ELEMS + (wm + i * 16 + fm) * HKE + fkb);
                bfr[i] = *reinterpret_cast<const bf16x8*>(lB + h * HALF_ELEMS + (wn + i * 16 + fm) * HKE + fkb);
            }
            #pragma unroll
            for (int i = 0; i < 4; ++i)
                #pragma unroll
                for (int j = 0; j < 4; ++j)
                    acc[i][j] = __builtin_amdgcn_mfma_f32_16x16x32_bf16(af[i], bfr[j], acc[i][j], 0, 0, 0);
        }
    }

    float* obuf = mlp_buf + (size_t)kh * MLP_SLAB;
    const int fr = (lane >> 4) * 4;
    #pragma unroll
    for (int i = 0; i < 4; ++i) {
        #pragma unroll
        for (int r = 0; r < 4; ++r) {
            const int gr = m0 + wm + i * 16 + fr + r;
            if (gr < count) {
                float* orow = obuf + (size_t)(e * N_TOK + gr) * C_DIM + n0 + wn + fm;
                #pragma unroll
                for (int j = 0; j < 4; ++j)
                    orow[j * 16] = acc[i][j][r];
            }
        }
    }
}

// ---------------- combine: out = ve contribs + weighted mlp contribs --------
__global__ void __launch_bounds__(256) combine_kernel(
    const int* __restrict__ token_ids, const float* __restrict__ vt,
    const float* __restrict__ vw, const int* __restrict__ te,
    const int* __restrict__ tp, const float* __restrict__ tw,
    const float* __restrict__ mlp_buf, float* __restrict__ out)
{
    const int n = blockIdx.x;
    const int c = threadIdx.x;
    const int t = token_ids[n];
    const float w0 = vw[n * 2 + 0];
    const float w1 = vw[n * 2 + 1];
    f32x4 v = {0.f, 0.f, 0.f, 0.f};
    if (w0 != 0.f)
        v += w0 * reinterpret_cast<const f32x4*>(vt + (size_t)t * C_DIM)[c];
    if (w1 != 0.f)
        v += w1 * reinterpret_cast<const f32x4*>(vt + ((size_t)V_DIM + t) * C_DIM)[c];
    #pragma unroll
    for (int k = 0; k < 2; ++k) {
        const int e = te[n * 2 + k];
        if (e >= 0) {
            const size_t slot = (size_t)(e * N_TOK + tp[n * 2 + k]) * C_DIM;
            f32x4 a = reinterpret_cast<const f32x4*>(mlp_buf + slot)[c];
            f32x4 b = reinterpret_cast<const f32x4*>(mlp_buf + MLP_SLAB + slot)[c];
            v += tw[n * 2 + k] * (a + b);
        }
    }
    reinterpret_cast<f32x4*>(out + (size_t)n * C_DIM)[c] = v;
}

extern "C" void kernel_launch(void* const* d_in, const int* in_sizes, int n_in,
                              void* d_out, int out_size, void* d_ws, size_t ws_size,
                              hipStream_t stream)
{
    const float* x         = (const float*)d_in[0];
    const int*   token_ids = (const int*)  d_in[1];
    const float* w_up      = (const float*)d_in[2];
    const float* w_down    = (const float*)d_in[3];
    const float* router_w  = (const float*)d_in[4];
    const float* router_b  = (const float*)d_in[5];
    const float* ve_tables = (const float*)d_in[6];
    float* out = (float*)d_out;

    char* ws = (char*)d_ws;
    size_t off = 0;
    __hip_bfloat16* hidden  = (__hip_bfloat16*)(ws + off); off += (size_t)NE_MLP * N_TOK * H_DIM * 2;  // 134 MB
    float*          mlp_buf = (float*)         (ws + off); off += 2 * MLP_SLAB * 4;                    // 268 MB
    __hip_bfloat16* xb      = (__hip_bfloat16*)(ws + off); off += (size_t)N_TOK * C_DIM * 2;
    __hip_bfloat16* wub     = (__hip_bfloat16*)(ws + off); off += (size_t)NE_MLP * H_DIM * C_DIM * 2;
    __hip_bfloat16* wdb     = (__hip_bfloat16*)(ws + off); off += (size_t)NE_MLP * C_DIM * H_DIM * 2;
    int*   tok_list = (int*)  (ws + off); off += (size_t)NE_MLP * N_TOK * 4;
    int*   te       = (int*)  (ws + off); off += (size_t)N_TOK * 2 * 4;
    int*   tp       = (int*)  (ws + off); off += (size_t)N_TOK * 2 * 4;
    float* tw       = (float*)(ws + off); off += (size_t)N_TOK * 2 * 4;
    float* vw       = (float*)(ws + off); off += (size_t)N_TOK * 2 * 4;
    int*   cnt      = (int*)  (ws + off); off += 64;

    hipMemsetAsync(cnt, 0, NE_MLP * sizeof(int), stream);

    cvt_kernel<<<(CVT_N0 + 2 * CVT_N1) / 256, 256, 0, stream>>>(
        x, w_up, w_down, xb, wub, wdb);
    router_kernel<<<N_TOK / 4, 256, 0, stream>>>(x, router_w, router_b,
                                                 tok_list, te, tp, tw, vw, cnt);
    up_kernel<<<dim3(H_DIM / BN, N_TOK / BM, NE_MLP), 256, 0, stream>>>(
        xb, wub, tok_list, cnt, hidden);
    down_kernel<<<dim3(C_DIM / BN, N_TOK / BM, NE_MLP * 2), 256, 0, stream>>>(
        hidden, wdb, cnt, mlp_buf);
    combine_kernel<<<N_TOK, 256, 0, stream>>>(token_ids, ve_tables, vw,
                                              te, tp, tw, mlp_buf, out);
}